// Round 8
// baseline (62.694 us; speedup 1.0000x reference)
//
#include <hip/hip_runtime.h>
#include <hip/hip_bf16.h>
#include <math.h>

#define N 1024
#define TB 16

typedef __attribute__((ext_vector_type(8))) short short8;
typedef __attribute__((ext_vector_type(4))) short short4v;
typedef __attribute__((ext_vector_type(4))) float f32x4;

// PReLU via max/min: max(v,0) + a*min(v,0)
__device__ __forceinline__ float prelu(float v, float a) {
    return fmaxf(v, 0.f) + a * fminf(v, 0.f);
}

// f32 -> bf16 RNE via hardware cvt (pairs into v_cvt_pk_bf16_f32)
__device__ __forceinline__ short f2bf(float f) {
    return (short)__bfloat16_as_ushort(__float2bfloat16(f));
}

// Barrier-free version: each wave owns 4 output rows and computes its whole
// dependency cone (6 h1 rows -> 5 h2 rows -> 4 out rows) in wave-private LDS.
// No __syncthreads anywhere; intra-wave LDS dependencies are lgkmcnt-ordered.
__global__ __launch_bounds__(256, 8) void precond_mfma(
    const float* __restrict__ xg, const int* __restrict__ maskg,
    const float* __restrict__ w1, const float* __restrict__ b1, const float* __restrict__ a1p,
    const float* __restrict__ w2, const float* __restrict__ b2, const float* __restrict__ a2p,
    const float* __restrict__ w3, const float* __restrict__ b3, const float* __restrict__ a3p,
    const float* __restrict__ w4, const float* __restrict__ b4p,
    float* __restrict__ out)
{
    const int tid = threadIdx.x;
    const int bz  = blockIdx.z;
    const int ty0 = blockIdx.y * TB, tx0 = blockIdx.x * TB;

    // ---- Early exit: tile entirely above the diagonal -> all zeros ----
    if (blockIdx.y < blockIdx.x) {
        int ty = tid >> 4, tx = tid & 15;
        out[((size_t)bz * N + ty0 + ty) * N + tx0 + tx] = 0.f;
        return;
    }

    // wave-private regions: [wave][...]
    __shared__ __align__(16) short h1s[4][108 * 8];   // 6 rows x 18 cols x 8ch
    __shared__ __align__(16) short h2lo[4][85 * 8];   // 5 rows x 17 cols, ch 0-7
    __shared__ __align__(16) short h2hi[4][85 * 8];   // 5 rows x 17 cols, ch 8-15
    __shared__ unsigned short msu[4][108];            // layer-1 mask (0/1)
    __shared__ unsigned short m2su[4][85];            // spread mask at h2 positions

    const int lane = tid & 63, wid = tid >> 6;
    const int c16 = lane & 15, g = lane >> 4;
    const int R0  = wid * 4;                          // wave's first output row

    const float a1 = a1p[0], a2 = a2p[0], a3 = a3p[0];
    const float b4 = b4p[0];
    const bool leftEdge  = (tx0 == 0);
    const bool rightEdge = (tx0 == N - TB);

    // --- per-lane weight fragments straight from global (L1-resident) ---
    // L2 A-frag: lane(c16,g) holds W2[oc=c16][k=g*8+j], k=khkw*8+ic -> w2[o][i][kh][kw]
    short8 a2f, a3f0, a3f1;
#pragma unroll
    for (int j = 0; j < 8; ++j) a2f[j] = f2bf(w2[c16 * 32 + j * 4 + g]);
    // L3 A-frags: k = khkw*16 + ic; a3f0 covers k=g*8..+7, a3f1 k=32+g*8..+7; oc>=8 zero
#pragma unroll
    for (int j = 0; j < 8; ++j) {
        int k0 = g * 8 + j, k1 = 32 + g * 8 + j;
        a3f0[j] = (c16 < 8) ? f2bf(w3[c16 * 64 + (k0 & 15) * 4 + (k0 >> 4)]) : (short)0;
        a3f1[j] = (c16 < 8) ? f2bf(w3[c16 * 64 + (k1 & 15) * 4 + (k1 >> 4)]) : (short)0;
    }
    f32x4 bias2, bias3;
    float w4r[4];
#pragma unroll
    for (int r = 0; r < 4; ++r) {
        bias2[r] = b2[g * 4 + r];
        bias3[r] = (g < 2) ? b3[g * 4 + r] : 0.f;
        w4r[r]   = (g < 2) ? w4[g * 4 + r] : 0.f;
    }

    // --- Phase A (per wave): h1 cone = 6 rows x 18 cols, masked+PReLU'd bf16 ---
    for (int p = lane; p < 108; p += 64) {
        int lr = p / 18, dx = p - lr * 18;
        int gy = ty0 + R0 - 1 + lr, gx = tx0 - 1 + dx;
        bool mb = false;
        float xv = 0.f;
        if ((unsigned)gy < N && (unsigned)gx < N) {
            size_t idx = ((size_t)bz * N + gy) * N + gx;
            mb = (maskg[idx] > 0);
            xv = xg[idx];
        }
        msu[wid][p] = (unsigned short)mb;
        short8 hv;
#pragma unroll
        for (int c = 0; c < 8; ++c) hv[c] = f2bf(prelu(fmaf(xv, w1[c], b1[c]), a1));
        if (!mb) hv = (short8)0;
        *(short8*)&h1s[wid][p * 8] = hv;
    }

    // --- Phase B (per wave): h2 cone = 5 rows x 17 cols = 85 positions, 6 MFMA groups ---
    {
        const int kh = g >> 1, kw = g & 1;
#pragma unroll
        for (int grp = 0; grp < 6; ++grp) {
            int p = grp * 16 + c16;
            bool valid = p < 85;
            int pc = valid ? p : 84;
            int lr2 = pc / 17, dx2 = pc - lr2 * 17;

            short8 bf = *(const short8*)&h1s[wid][((lr2 + kh) * 18 + dx2 + kw) * 8];
            f32x4 acc = __builtin_amdgcn_mfma_f32_16x16x32_bf16(a2f, bf, bias2, 0, 0, 0);

            int mb = lr2 * 18 + dx2;
            unsigned m2 = (unsigned)(msu[wid][mb]      | msu[wid][mb + 1] |
                                     msu[wid][mb + 18] | msu[wid][mb + 19]);
            if ((leftEdge && dx2 == 0) || (rightEdge && dx2 == 16)) m2 = 0;

            short4v hv;
#pragma unroll
            for (int r = 0; r < 4; ++r) hv[r] = f2bf(prelu(acc[r], a2));
            if (m2 == 0) { hv[0] = 0; hv[1] = 0; hv[2] = 0; hv[3] = 0; }

            if (valid) {
                short* dst = (g & 2) ? &h2hi[wid][0] : &h2lo[wid][0];
                *(short4v*)&dst[pc * 8 + (g & 1) * 4] = hv;
                if (g == 0) m2su[wid][pc] = (unsigned short)(m2 != 0);
            }
        }
    }

    // --- Phase C (per wave): 4 output rows; 2 chained MFMAs (K=64) + layer4 + epilogue ---
    {
        const int kw = g >> 1, ic8 = g & 1;
        const short* h2sel = ic8 ? &h2hi[wid][0] : &h2lo[wid][0];

#pragma unroll
        for (int j = 0; j < 4; ++j) {
            short8 bf0 = *(const short8*)&h2sel[((j + 0) * 17 + c16 + kw) * 8];
            short8 bf1 = *(const short8*)&h2sel[((j + 1) * 17 + c16 + kw) * 8];
            f32x4 acc = __builtin_amdgcn_mfma_f32_16x16x32_bf16(a3f0, bf0, bias3, 0, 0, 0);
            acc = __builtin_amdgcn_mfma_f32_16x16x32_bf16(a3f1, bf1, acc, 0, 0, 0);

            float partial = 0.f;
#pragma unroll
            for (int r = 0; r < 4; ++r) partial = fmaf(prelu(acc[r], a3), w4r[r], partial);
            partial += __shfl_xor(partial, 16, 64);
            partial += __shfl_xor(partial, 32, 64);

            if (g == 0) {
                int mb = j * 17 + c16;
                unsigned m3 = (unsigned)(m2su[wid][mb]      | m2su[wid][mb + 1] |
                                         m2su[wid][mb + 17] | m2su[wid][mb + 18]);
                float outv = m3 ? (partial + b4) : 0.f;
                int y = ty0 + R0 + j, x = tx0 + c16;
                if (y < x) {
                    outv = 0.f;
                } else if (y == x && m3) {
                    outv = fmaxf(outv, 0.f) + log1pf(expf(-fabsf(outv)));
                }
                out[((size_t)bz * N + y) * N + x] = outv;
            }
        }
    }
}

extern "C" void kernel_launch(void* const* d_in, const int* in_sizes, int n_in,
                              void* d_out, int out_size, void* d_ws, size_t ws_size,
                              hipStream_t stream) {
    const float* x    = (const float*)d_in[0];
    const int*   mask = (const int*)  d_in[1];
    const float* w1   = (const float*)d_in[2];
    const float* b1   = (const float*)d_in[3];
    const float* a1   = (const float*)d_in[4];
    const float* w2   = (const float*)d_in[5];
    const float* b2   = (const float*)d_in[6];
    const float* a2   = (const float*)d_in[7];
    const float* w3   = (const float*)d_in[8];
    const float* b3   = (const float*)d_in[9];
    const float* a3   = (const float*)d_in[10];
    const float* w4   = (const float*)d_in[11];
    const float* b4   = (const float*)d_in[12];
    float* out = (float*)d_out;

    dim3 grid(N / TB, N / TB, 2);
    precond_mfma<<<grid, 256, 0, stream>>>(x, mask, w1, b1, a1, w2, b2, a2,
                                           w3, b3, a3, w4, b4, out);
}